// Round 1
// 462.055 us; speedup vs baseline: 1.0308x; 1.0308x over previous
//
#include <hip/hip_runtime.h>
#include <hip/hip_bf16.h>

// Problem: B=16, C=256, H=W=64 -> N=4096.
// ref: attn = sum_s softmax(max-E_s) over last dim, E_s = Q K_s^T (reduce over N)
//      out  = gamma * (conv_w @ (attn @ Q) + bias) + x
// fused as: M = conv_w @ attn  (tiny GEMM), out = gamma*(M @ Q + bias) + x
//
// v2 changes vs previous session best (476 us):
//  - out_kernel: LDS transpose of Q removed from the hot loop (was 128 scalar
//    ds_write_u16/thread + 3.67M bank-conflict cycles -> 109us @ 1.5 TB/s).
//    Q^T is now materialized ONCE in bf16 (convert_xT) and out_kernel is a
//    zero-LDS, zero-barrier register GEMM.
//  - energy_kernel: K-split x4 (was 192 blocks on 256 CUs = 1 block/CU);
//    now 768 blocks = 3 blocks/CU. Partials summed in softmax.
//  - softmax: barrier-tree (48 __syncthreads/block) -> wave shuffle reduce.

#define B_ 16
#define C_ 256
#define N_ 4096
#define KSPLIT 4
#define KCHUNK (N_ / KSPLIT)   // 1024

#define MODE_BF16 0
#define MODE_F32  1

typedef __bf16 bf16_t;
typedef bf16_t bf16x8 __attribute__((ext_vector_type(8)));
typedef float  f32x4  __attribute__((ext_vector_type(4)));

#define MFMA(a, b, c) __builtin_amdgcn_mfma_f32_16x16x32_bf16(a, b, c, 0, 0, 0)

// Scratch (module-load allocated; no ws_size dependence; graph-safe).
__device__ int    g_mode;
__device__ bf16_t g_in[3][(size_t)B_ * C_ * N_];   // canonical x,y,z (100.7 MB)
__device__ bf16_t g_qT[(size_t)B_ * N_ * C_];      // x transposed [b][n][c] (33.5 MB)
__device__ bf16_t g_cw[C_ * C_];
__device__ float  g_cb[C_];
__device__ float  g_gamma;
__device__ float  g_Ep[(size_t)KSPLIT * 3 * B_ * C_ * C_];  // partial E, 50.3 MB
__device__ bf16_t g_attnT[(size_t)B_ * C_ * C_];
__device__ bf16_t g_M[(size_t)B_ * C_ * C_];

// ---------------------------------------------------------------------------
// Kernel 0: dtype sniff. fp32 N(0,1) data -> abs bits <= ~0x40C00000.
// bf16 pairs misread as fp32 -> exponent field from bf16 payload bits,
// values ~1e37 almost surely. Threshold 1024.0f separates cleanly.
// ---------------------------------------------------------------------------
__global__ __launch_bounds__(256) void detect_kernel(const float* __restrict__ xf)
{
  __shared__ unsigned red[256];
  const int t = threadIdx.x;
  unsigned m = 0;
  for (int i = t; i < 4096; i += 256)
    m = max(m, __float_as_uint(xf[i]) & 0x7fffffffu);
  red[t] = m;
  __syncthreads();
  for (int s = 128; s > 0; s >>= 1) {
    if (t < s) red[t] = max(red[t], red[t + s]);
    __syncthreads();
  }
  if (t == 0) g_mode = (red[0] > 0x44800000u) ? MODE_BF16 : MODE_F32;
}

// ---------------------------------------------------------------------------
// Kernel 0b: canonicalize y,z into bf16 staging. grid (8192, 2).
// ---------------------------------------------------------------------------
__global__ __launch_bounds__(256) void convert_big(
    const void* __restrict__ y, const void* __restrict__ z)
{
  const void* src = blockIdx.y == 0 ? y : z;
  bf16_t* dst = g_in[1 + blockIdx.y];
  const size_t idx = ((size_t)blockIdx.x * 256 + threadIdx.x) * 8;
  if (g_mode == MODE_F32) {
    const float* s = (const float*)src + idx;
    float4 a = *(const float4*)s;
    float4 b = *(const float4*)(s + 4);
    bf16x8 v;
    v[0] = (bf16_t)a.x; v[1] = (bf16_t)a.y; v[2] = (bf16_t)a.z; v[3] = (bf16_t)a.w;
    v[4] = (bf16_t)b.x; v[5] = (bf16_t)b.y; v[6] = (bf16_t)b.z; v[7] = (bf16_t)b.w;
    *(bf16x8*)(dst + idx) = v;
  } else {
    *(bf16x8*)(dst + idx) = *(const bf16x8*)((const bf16_t*)src + idx);
  }
}

// ---------------------------------------------------------------------------
// Kernel 0d: canonicalize x into bf16 AND materialize x^T [b][n][c] in bf16.
// 64x64 tiles via LDS. grid (N/64, C/64, B).
// ---------------------------------------------------------------------------
__global__ __launch_bounds__(256) void convert_xT(const void* __restrict__ x)
{
  __shared__ bf16_t Ts[64][72];   // [c_local][n_local], padded
  const int t  = threadIdx.x;
  const int r  = t >> 3;          // 0..31
  const int co = (t & 7) * 8;     // 0..56
  const int n0 = blockIdx.x * 64;
  const int c0 = blockIdx.y * 64;
  const int b  = blockIdx.z;
  const size_t base = (size_t)b * C_ * N_;

  bf16x8 v[2];
  if (g_mode == MODE_F32) {
#pragma unroll
    for (int p = 0; p < 2; ++p) {
      const float* s = (const float*)x + base + (size_t)(c0 + r + p * 32) * N_ + n0 + co;
      float4 a = *(const float4*)s;
      float4 b4 = *(const float4*)(s + 4);
      bf16x8 w;
      w[0] = (bf16_t)a.x; w[1] = (bf16_t)a.y; w[2] = (bf16_t)a.z; w[3] = (bf16_t)a.w;
      w[4] = (bf16_t)b4.x; w[5] = (bf16_t)b4.y; w[6] = (bf16_t)b4.z; w[7] = (bf16_t)b4.w;
      v[p] = w;
    }
  } else {
#pragma unroll
    for (int p = 0; p < 2; ++p)
      v[p] = *(const bf16x8*)((const bf16_t*)x + base + (size_t)(c0 + r + p * 32) * N_ + n0 + co);
  }

  // write-through normal bf16 staging + stage tile in LDS
#pragma unroll
  for (int p = 0; p < 2; ++p) {
    *(bf16x8*)(g_in[0] + base + (size_t)(c0 + r + p * 32) * N_ + n0 + co) = v[p];
    *(bf16x8*)(&Ts[r + p * 32][co]) = v[p];
  }
  __syncthreads();

  // write transposed rows: QT[b][n0+n][c0+co .. +7]
#pragma unroll
  for (int p = 0; p < 2; ++p) {
    const int n = r + p * 32;
    bf16x8 w;
#pragma unroll
    for (int j = 0; j < 8; ++j) w[j] = Ts[co + j][n];
    *(bf16x8*)(g_qT + (size_t)b * N_ * C_ + (size_t)(n0 + n) * C_ + c0 + co) = w;
  }
}

// ---------------------------------------------------------------------------
// Kernel 0c: canonicalize conv_w (bf16), conv_b + gamma (fp32). 1 block.
// ---------------------------------------------------------------------------
__global__ __launch_bounds__(256) void convert_params(
    const void* __restrict__ cw, const void* __restrict__ cb,
    const void* __restrict__ gm)
{
  const int t = threadIdx.x;
  if (g_mode == MODE_F32) {
    for (int i = t * 8; i < C_ * C_; i += 256 * 8) {
      const float* s = (const float*)cw + i;
      float4 a = *(const float4*)s;
      float4 b = *(const float4*)(s + 4);
      bf16x8 v;
      v[0] = (bf16_t)a.x; v[1] = (bf16_t)a.y; v[2] = (bf16_t)a.z; v[3] = (bf16_t)a.w;
      v[4] = (bf16_t)b.x; v[5] = (bf16_t)b.y; v[6] = (bf16_t)b.z; v[7] = (bf16_t)b.w;
      *(bf16x8*)(g_cw + i) = v;
    }
    if (t < C_) g_cb[t] = ((const float*)cb)[t];
    if (t == 0) g_gamma = ((const float*)gm)[0];
  } else {
    for (int i = t * 8; i < C_ * C_; i += 256 * 8)
      *(bf16x8*)(g_cw + i) = *(const bf16x8*)((const bf16_t*)cw + i);
    if (t < C_) g_cb[t] = (float)((const bf16_t*)cb)[t];
    if (t == 0) g_gamma = (float)((const bf16_t*)gm)[0];
  }
}

// ---------------------------------------------------------------------------
// Kernel 1: Ep[kc][s][b][c][d] = sum_{n in chunk} Q[b,c,n] * Ksrc_s[b,d,n]
// 128x128 tile, 4 waves of 64x64, BK=64, LDS-staged NT GEMM, K split x4.
// grid (4 tiles * KSPLIT, 3, B).
// ---------------------------------------------------------------------------
__global__ __launch_bounds__(256) void energy_kernel()
{
  const int tile = blockIdx.x & 3;   // 0..3
  const int kc   = blockIdx.x >> 2;  // 0..3
  const int s    = blockIdx.y;       // 0..2
  const int b    = blockIdx.z;       // 0..15

  const bf16_t* q = g_in[0] + (size_t)b * C_ * N_;
  const bf16_t* k = g_in[s] + (size_t)b * C_ * N_;

  const int tile_m = (tile & 1) * 128;
  const int tile_d = (tile >> 1) * 128;

  __shared__ bf16_t As[128][72];  // stride 144 B: 16B-aligned rows, non-pow2
  __shared__ bf16_t Bs[128][72];

  const int tid  = threadIdx.x;
  const int w    = tid >> 6;
  const int lane = tid & 63;
  const int wm   = (w & 1) * 64;
  const int wd   = (w >> 1) * 64;
  const int lrow = lane & 15;
  const int lk   = (lane >> 4) * 8;

  const int srow = tid >> 3;        // 0..31
  const int soff = (tid & 7) * 8;   // 0..56

  f32x4 acc[4][4] = {};

  const int kbeg = kc * KCHUNK;
  for (int k0 = kbeg; k0 < kbeg + KCHUNK; k0 += 64) {
    bf16x8 av[4], bv[4];
#pragma unroll
    for (int i = 0; i < 4; ++i) {
      int r = srow + i * 32;
      av[i] = *(const bf16x8*)(q + (size_t)(tile_m + r) * N_ + k0 + soff);
      bv[i] = *(const bf16x8*)(k + (size_t)(tile_d + r) * N_ + k0 + soff);
    }
    __syncthreads();
#pragma unroll
    for (int i = 0; i < 4; ++i) {
      int r = srow + i * 32;
      *(bf16x8*)(&As[r][soff]) = av[i];
      *(bf16x8*)(&Bs[r][soff]) = bv[i];
    }
    __syncthreads();
#pragma unroll
    for (int kk = 0; kk < 64; kk += 32) {
      bf16x8 af[4], bfr[4];
#pragma unroll
      for (int i = 0; i < 4; ++i)
        af[i] = *(const bf16x8*)(&As[wm + i * 16 + lrow][kk + lk]);
#pragma unroll
      for (int j = 0; j < 4; ++j)
        bfr[j] = *(const bf16x8*)(&Bs[wd + j * 16 + lrow][kk + lk]);
#pragma unroll
      for (int i = 0; i < 4; ++i)
#pragma unroll
        for (int j = 0; j < 4; ++j)
          acc[i][j] = MFMA(af[i], bfr[j], acc[i][j]);
    }
  }

  // C/D layout: col = lane&15, row = (lane>>4)*4 + r
  float* Eb = g_Ep + (((size_t)kc * 3 + s) * B_ + b) * (size_t)C_ * C_;
  const int orow0 = tile_m + wm + (lane >> 4) * 4;
  const int ocol0 = tile_d + wd + (lane & 15);
#pragma unroll
  for (int i = 0; i < 4; ++i)
#pragma unroll
    for (int j = 0; j < 4; ++j)
#pragma unroll
      for (int r = 0; r < 4; ++r)
        Eb[(size_t)(orow0 + i * 16 + r) * C_ + (ocol0 + j * 16)] = acc[i][j][r];
}

// ---------------------------------------------------------------------------
// Kernel 2: attnT[b][d][c] = sum_s exp(min_d E_s - E_s[c,d]) / Z_s   (bf16)
// One wave per c-row (4 rows/block), shuffle reductions, sums KSPLIT partials.
// grid (C/4, B).
// ---------------------------------------------------------------------------
__global__ __launch_bounds__(256) void softmax_kernel()
{
  const int b    = blockIdx.y;
  const int c    = blockIdx.x * 4 + (threadIdx.x >> 6);
  const int lane = threadIdx.x & 63;
  const int d0   = lane * 4;

  float a0 = 0.f, a1 = 0.f, a2 = 0.f, a3 = 0.f;
#pragma unroll
  for (int s = 0; s < 3; ++s) {
    float e0 = 0.f, e1 = 0.f, e2 = 0.f, e3 = 0.f;
#pragma unroll
    for (int kc = 0; kc < KSPLIT; ++kc) {
      const float4 ep = *(const float4*)(
          g_Ep + ((((size_t)kc * 3 + s) * B_ + b) * C_ + c) * (size_t)C_ + d0);
      e0 += ep.x; e1 += ep.y; e2 += ep.z; e3 += ep.w;
    }
    float mn = fminf(fminf(e0, e1), fminf(e2, e3));
#pragma unroll
    for (int m = 32; m > 0; m >>= 1) mn = fminf(mn, __shfl_xor(mn, m));
    const float p0 = __expf(mn - e0);   // <= 1; min term gives exactly 1
    const float p1 = __expf(mn - e1);
    const float p2 = __expf(mn - e2);
    const float p3 = __expf(mn - e3);
    float Z = p0 + p1 + p2 + p3;
#pragma unroll
    for (int m = 32; m > 0; m >>= 1) Z += __shfl_xor(Z, m);
    const float rZ = 1.0f / Z;
    a0 += p0 * rZ; a1 += p1 * rZ; a2 += p2 * rZ; a3 += p3 * rZ;
  }
  bf16_t* At = g_attnT + (size_t)b * C_ * C_;   // [d][c], transposed for kernel 3
  At[(size_t)(d0 + 0) * C_ + c] = (bf16_t)a0;
  At[(size_t)(d0 + 1) * C_ + c] = (bf16_t)a1;
  At[(size_t)(d0 + 2) * C_ + c] = (bf16_t)a2;
  At[(size_t)(d0 + 3) * C_ + c] = (bf16_t)a3;
}

// ---------------------------------------------------------------------------
// Kernel 3: M[b][o][d] = sum_c conv_w[o,c] * attnT[b][d][c]   (bf16 out)
// ---------------------------------------------------------------------------
__global__ __launch_bounds__(256) void mconv_kernel()
{
  const int tile = blockIdx.x;  // 0..3
  const int b    = blockIdx.y;
  const int tile_o = (tile & 1) * 128;
  const int tile_d = (tile >> 1) * 128;
  const int tid  = threadIdx.x;
  const int w    = tid >> 6;
  const int lane = tid & 63;
  const int wo   = (w & 1) * 64;
  const int wd   = (w >> 1) * 64;
  const int lrow = lane & 15;
  const int lk   = (lane >> 4) * 8;

  const bf16_t* At = g_attnT + (size_t)b * C_ * C_;
  f32x4 acc[4][4] = {};

  for (int c0 = 0; c0 < C_; c0 += 32) {
    bf16x8 af[4], bfr[4];
#pragma unroll
    for (int i = 0; i < 4; ++i)
      af[i] = *(const bf16x8*)(g_cw + (size_t)(tile_o + wo + i * 16 + lrow) * C_ + c0 + lk);
#pragma unroll
    for (int j = 0; j < 4; ++j)
      bfr[j] = *(const bf16x8*)(At + (size_t)(tile_d + wd + j * 16 + lrow) * C_ + c0 + lk);
#pragma unroll
    for (int i = 0; i < 4; ++i)
#pragma unroll
      for (int j = 0; j < 4; ++j)
        acc[i][j] = MFMA(af[i], bfr[j], acc[i][j]);
  }

  bf16_t* Mb = g_M + (size_t)b * C_ * C_;
  const int orow0 = tile_o + wo + (lane >> 4) * 4;
  const int ocol0 = tile_d + wd + (lane & 15);
#pragma unroll
  for (int i = 0; i < 4; ++i)
#pragma unroll
    for (int j = 0; j < 4; ++j)
#pragma unroll
      for (int r = 0; r < 4; ++r)
        Mb[(size_t)(orow0 + i * 16 + r) * C_ + (ocol0 + j * 16)] = (bf16_t)acc[i][j][r];
}

// ---------------------------------------------------------------------------
// Kernel 4: out[b][o][n] = gamma*(sum_d M[b,o,d]*Q[b,d,n] + bias[o]) + x[b,o,n]
// 128(o) x 128(n) tile, BK=32. Zero LDS, zero barriers: both operands read as
// bf16x8 rows from global (M rows; Q^T rows from g_qT).
// ---------------------------------------------------------------------------
__global__ __launch_bounds__(256) void out_kernel(
    const void* __restrict__ xraw, void* __restrict__ outraw)
{
  const int n0 = blockIdx.x * 128;  // 0..31
  const int o0 = blockIdx.y * 128;  // 0..1
  const int b  = blockIdx.z;

  const int tid  = threadIdx.x;
  const int w    = tid >> 6;
  const int lane = tid & 63;
  const int wo   = (w & 1) * 64;
  const int wn   = (w >> 1) * 64;
  const int lrow = lane & 15;
  const int lk   = (lane >> 4) * 8;

  const bf16_t* aptr = g_M  + (size_t)b * C_ * C_ + (size_t)(o0 + wo + lrow) * C_ + lk;
  const bf16_t* bptr = g_qT + (size_t)b * N_ * C_ + (size_t)(n0 + wn + lrow) * C_ + lk;

  f32x4 acc[4][4] = {};

#pragma unroll 2
  for (int d0 = 0; d0 < C_; d0 += 32) {
    bf16x8 af[4], bfr[4];
#pragma unroll
    for (int i = 0; i < 4; ++i)
      af[i] = *(const bf16x8*)(aptr + (size_t)i * 16 * C_ + d0);
#pragma unroll
    for (int j = 0; j < 4; ++j)
      bfr[j] = *(const bf16x8*)(bptr + (size_t)j * 16 * C_ + d0);
#pragma unroll
    for (int i = 0; i < 4; ++i)
#pragma unroll
      for (int j = 0; j < 4; ++j)
        acc[i][j] = MFMA(af[i], bfr[j], acc[i][j]);
  }

  const float g = g_gamma;
  const int mode = g_mode;
  const int orow0 = o0 + wo + (lane >> 4) * 4;
  const int ocol0 = n0 + wn + (lane & 15);
  const size_t base = (size_t)b * C_ * N_;

#pragma unroll
  for (int i = 0; i < 4; ++i)
#pragma unroll
    for (int j = 0; j < 4; ++j)
#pragma unroll
      for (int r = 0; r < 4; ++r) {
        int o = orow0 + i * 16 + r;
        int n = ocol0 + j * 16;
        size_t off = base + (size_t)o * N_ + n;
        float v = g * (acc[i][j][r] + g_cb[o]);
        if (mode == MODE_F32) {
          ((float*)outraw)[off] = v + ((const float*)xraw)[off];
        } else {
          ((bf16_t*)outraw)[off] =
              (bf16_t)(v + (float)((const bf16_t*)xraw)[off]);
        }
      }
}

// ---------------------------------------------------------------------------
extern "C" void kernel_launch(void* const* d_in, const int* in_sizes, int n_in,
                              void* d_out, int out_size, void* d_ws, size_t ws_size,
                              hipStream_t stream)
{
  const void* x  = d_in[0];
  const void* y  = d_in[1];
  const void* z  = d_in[2];
  const void* cw = d_in[3];
  const void* cb = d_in[4];
  const void* gm = d_in[5];
  (void)d_ws; (void)ws_size;

  detect_kernel  <<<1,                       256, 0, stream>>>((const float*)x);
  convert_big    <<<dim3(8192, 2),           256, 0, stream>>>(y, z);
  convert_params <<<1,                       256, 0, stream>>>(cw, cb, gm);
  convert_xT     <<<dim3(N_ / 64, C_ / 64, B_), 256, 0, stream>>>(x);
  energy_kernel  <<<dim3(4 * KSPLIT, 3, B_), 256, 0, stream>>>();
  softmax_kernel <<<dim3(C_ / 4, B_),        256, 0, stream>>>();
  mconv_kernel   <<<dim3(4, B_),             256, 0, stream>>>();
  out_kernel     <<<dim3(N_ / 128, 2, B_),   256, 0, stream>>>(x, d_out);
}

// Round 2
// 406.284 us; speedup vs baseline: 1.1723x; 1.1373x over previous
//
#include <hip/hip_runtime.h>
#include <hip/hip_bf16.h>

// Problem: B=16, C=256, H=W=64 -> N=4096.
// ref: attn = sum_s softmax(max-E_s) over last dim, E_s = Q K_s^T (reduce over N)
//      out  = gamma * (conv_w @ (attn @ Q) + bias) + x
// fused as: M = conv_w @ attn  (tiny GEMM), P = M @ Q, out = gamma*(P+bias)+x
//
// v3 changes vs v2 (462 us):
//  - out_kernel (119 us @ 1.2 TB/s, latency-bound, MfmaUtil 2.7%) split into:
//      pmq_kernel: P = M @ Q^T, exact clone of energy_kernel's proven
//        LDS-staged structure (>3.8 TB/s effective in this program), bf16 out.
//      epilogue_kernel: out = gamma*(P+bias)+x, pure streaming, float4/bf16x8.
//    This both removes the fused scalar epilogue from the MFMA kernel and
//    isolates GEMM vs epilogue in the next profile.

#define B_ 16
#define C_ 256
#define N_ 4096
#define KSPLIT 4
#define KCHUNK (N_ / KSPLIT)   // 1024

#define MODE_BF16 0
#define MODE_F32  1

typedef __bf16 bf16_t;
typedef bf16_t bf16x8 __attribute__((ext_vector_type(8)));
typedef float  f32x4  __attribute__((ext_vector_type(4)));

#define MFMA(a, b, c) __builtin_amdgcn_mfma_f32_16x16x32_bf16(a, b, c, 0, 0, 0)

// Scratch (module-load allocated; no ws_size dependence; graph-safe).
__device__ int    g_mode;
__device__ bf16_t g_in[3][(size_t)B_ * C_ * N_];   // canonical x,y,z (100.7 MB)
__device__ bf16_t g_qT[(size_t)B_ * N_ * C_];      // x transposed [b][n][c] (33.5 MB)
__device__ bf16_t g_cw[C_ * C_];
__device__ float  g_cb[C_];
__device__ float  g_gamma;
__device__ float  g_Ep[(size_t)KSPLIT * 3 * B_ * C_ * C_];  // partial E, 50.3 MB
__device__ bf16_t g_attnT[(size_t)B_ * C_ * C_];
__device__ bf16_t g_M[(size_t)B_ * C_ * C_];
__device__ bf16_t g_P[(size_t)B_ * C_ * N_];       // P = M @ Q (33.5 MB)

// ---------------------------------------------------------------------------
// Kernel 0: dtype sniff. fp32 N(0,1) data -> abs bits <= ~0x40C00000.
// bf16 pairs misread as fp32 -> exponent field from bf16 payload bits,
// values ~1e37 almost surely. Threshold 1024.0f separates cleanly.
// ---------------------------------------------------------------------------
__global__ __launch_bounds__(256) void detect_kernel(const float* __restrict__ xf)
{
  __shared__ unsigned red[256];
  const int t = threadIdx.x;
  unsigned m = 0;
  for (int i = t; i < 4096; i += 256)
    m = max(m, __float_as_uint(xf[i]) & 0x7fffffffu);
  red[t] = m;
  __syncthreads();
  for (int s = 128; s > 0; s >>= 1) {
    if (t < s) red[t] = max(red[t], red[t + s]);
    __syncthreads();
  }
  if (t == 0) g_mode = (red[0] > 0x44800000u) ? MODE_BF16 : MODE_F32;
}

// ---------------------------------------------------------------------------
// Kernel 0b: canonicalize y,z into bf16 staging. grid (8192, 2).
// ---------------------------------------------------------------------------
__global__ __launch_bounds__(256) void convert_big(
    const void* __restrict__ y, const void* __restrict__ z)
{
  const void* src = blockIdx.y == 0 ? y : z;
  bf16_t* dst = g_in[1 + blockIdx.y];
  const size_t idx = ((size_t)blockIdx.x * 256 + threadIdx.x) * 8;
  if (g_mode == MODE_F32) {
    const float* s = (const float*)src + idx;
    float4 a = *(const float4*)s;
    float4 b = *(const float4*)(s + 4);
    bf16x8 v;
    v[0] = (bf16_t)a.x; v[1] = (bf16_t)a.y; v[2] = (bf16_t)a.z; v[3] = (bf16_t)a.w;
    v[4] = (bf16_t)b.x; v[5] = (bf16_t)b.y; v[6] = (bf16_t)b.z; v[7] = (bf16_t)b.w;
    *(bf16x8*)(dst + idx) = v;
  } else {
    *(bf16x8*)(dst + idx) = *(const bf16x8*)((const bf16_t*)src + idx);
  }
}

// ---------------------------------------------------------------------------
// Kernel 0d: canonicalize x into bf16 AND materialize x^T [b][n][c] in bf16.
// 64x64 tiles via LDS. grid (N/64, C/64, B).
// ---------------------------------------------------------------------------
__global__ __launch_bounds__(256) void convert_xT(const void* __restrict__ x)
{
  __shared__ bf16_t Ts[64][72];   // [c_local][n_local], padded
  const int t  = threadIdx.x;
  const int r  = t >> 3;          // 0..31
  const int co = (t & 7) * 8;     // 0..56
  const int n0 = blockIdx.x * 64;
  const int c0 = blockIdx.y * 64;
  const int b  = blockIdx.z;
  const size_t base = (size_t)b * C_ * N_;

  bf16x8 v[2];
  if (g_mode == MODE_F32) {
#pragma unroll
    for (int p = 0; p < 2; ++p) {
      const float* s = (const float*)x + base + (size_t)(c0 + r + p * 32) * N_ + n0 + co;
      float4 a = *(const float4*)s;
      float4 b4 = *(const float4*)(s + 4);
      bf16x8 w;
      w[0] = (bf16_t)a.x; w[1] = (bf16_t)a.y; w[2] = (bf16_t)a.z; w[3] = (bf16_t)a.w;
      w[4] = (bf16_t)b4.x; w[5] = (bf16_t)b4.y; w[6] = (bf16_t)b4.z; w[7] = (bf16_t)b4.w;
      v[p] = w;
    }
  } else {
#pragma unroll
    for (int p = 0; p < 2; ++p)
      v[p] = *(const bf16x8*)((const bf16_t*)x + base + (size_t)(c0 + r + p * 32) * N_ + n0 + co);
  }

  // write-through normal bf16 staging + stage tile in LDS
#pragma unroll
  for (int p = 0; p < 2; ++p) {
    *(bf16x8*)(g_in[0] + base + (size_t)(c0 + r + p * 32) * N_ + n0 + co) = v[p];
    *(bf16x8*)(&Ts[r + p * 32][co]) = v[p];
  }
  __syncthreads();

  // write transposed rows: QT[b][n0+n][c0+co .. +7]
#pragma unroll
  for (int p = 0; p < 2; ++p) {
    const int n = r + p * 32;
    bf16x8 w;
#pragma unroll
    for (int j = 0; j < 8; ++j) w[j] = Ts[co + j][n];
    *(bf16x8*)(g_qT + (size_t)b * N_ * C_ + (size_t)(n0 + n) * C_ + c0 + co) = w;
  }
}

// ---------------------------------------------------------------------------
// Kernel 0c: canonicalize conv_w (bf16), conv_b + gamma (fp32). 1 block.
// ---------------------------------------------------------------------------
__global__ __launch_bounds__(256) void convert_params(
    const void* __restrict__ cw, const void* __restrict__ cb,
    const void* __restrict__ gm)
{
  const int t = threadIdx.x;
  if (g_mode == MODE_F32) {
    for (int i = t * 8; i < C_ * C_; i += 256 * 8) {
      const float* s = (const float*)cw + i;
      float4 a = *(const float4*)s;
      float4 b = *(const float4*)(s + 4);
      bf16x8 v;
      v[0] = (bf16_t)a.x; v[1] = (bf16_t)a.y; v[2] = (bf16_t)a.z; v[3] = (bf16_t)a.w;
      v[4] = (bf16_t)b.x; v[5] = (bf16_t)b.y; v[6] = (bf16_t)b.z; v[7] = (bf16_t)b.w;
      *(bf16x8*)(g_cw + i) = v;
    }
    if (t < C_) g_cb[t] = ((const float*)cb)[t];
    if (t == 0) g_gamma = ((const float*)gm)[0];
  } else {
    for (int i = t * 8; i < C_ * C_; i += 256 * 8)
      *(bf16x8*)(g_cw + i) = *(const bf16x8*)((const bf16_t*)cw + i);
    if (t < C_) g_cb[t] = (float)((const bf16_t*)cb)[t];
    if (t == 0) g_gamma = (float)((const bf16_t*)gm)[0];
  }
}

// ---------------------------------------------------------------------------
// Kernel 1: Ep[kc][s][b][c][d] = sum_{n in chunk} Q[b,c,n] * Ksrc_s[b,d,n]
// 128x128 tile, 4 waves of 64x64, BK=64, LDS-staged NT GEMM, K split x4.
// grid (4 tiles * KSPLIT, 3, B).
// ---------------------------------------------------------------------------
__global__ __launch_bounds__(256) void energy_kernel()
{
  const int tile = blockIdx.x & 3;   // 0..3
  const int kc   = blockIdx.x >> 2;  // 0..3
  const int s    = blockIdx.y;       // 0..2
  const int b    = blockIdx.z;       // 0..15

  const bf16_t* q = g_in[0] + (size_t)b * C_ * N_;
  const bf16_t* k = g_in[s] + (size_t)b * C_ * N_;

  const int tile_m = (tile & 1) * 128;
  const int tile_d = (tile >> 1) * 128;

  __shared__ bf16_t As[128][72];  // stride 144 B: 16B-aligned rows, non-pow2
  __shared__ bf16_t Bs[128][72];

  const int tid  = threadIdx.x;
  const int w    = tid >> 6;
  const int lane = tid & 63;
  const int wm   = (w & 1) * 64;
  const int wd   = (w >> 1) * 64;
  const int lrow = lane & 15;
  const int lk   = (lane >> 4) * 8;

  const int srow = tid >> 3;        // 0..31
  const int soff = (tid & 7) * 8;   // 0..56

  f32x4 acc[4][4] = {};

  const int kbeg = kc * KCHUNK;
  for (int k0 = kbeg; k0 < kbeg + KCHUNK; k0 += 64) {
    bf16x8 av[4], bv[4];
#pragma unroll
    for (int i = 0; i < 4; ++i) {
      int r = srow + i * 32;
      av[i] = *(const bf16x8*)(q + (size_t)(tile_m + r) * N_ + k0 + soff);
      bv[i] = *(const bf16x8*)(k + (size_t)(tile_d + r) * N_ + k0 + soff);
    }
    __syncthreads();
#pragma unroll
    for (int i = 0; i < 4; ++i) {
      int r = srow + i * 32;
      *(bf16x8*)(&As[r][soff]) = av[i];
      *(bf16x8*)(&Bs[r][soff]) = bv[i];
    }
    __syncthreads();
#pragma unroll
    for (int kk = 0; kk < 64; kk += 32) {
      bf16x8 af[4], bfr[4];
#pragma unroll
      for (int i = 0; i < 4; ++i)
        af[i] = *(const bf16x8*)(&As[wm + i * 16 + lrow][kk + lk]);
#pragma unroll
      for (int j = 0; j < 4; ++j)
        bfr[j] = *(const bf16x8*)(&Bs[wd + j * 16 + lrow][kk + lk]);
#pragma unroll
      for (int i = 0; i < 4; ++i)
#pragma unroll
        for (int j = 0; j < 4; ++j)
          acc[i][j] = MFMA(af[i], bfr[j], acc[i][j]);
    }
  }

  // C/D layout: col = lane&15, row = (lane>>4)*4 + r
  float* Eb = g_Ep + (((size_t)kc * 3 + s) * B_ + b) * (size_t)C_ * C_;
  const int orow0 = tile_m + wm + (lane >> 4) * 4;
  const int ocol0 = tile_d + wd + (lane & 15);
#pragma unroll
  for (int i = 0; i < 4; ++i)
#pragma unroll
    for (int j = 0; j < 4; ++j)
#pragma unroll
      for (int r = 0; r < 4; ++r)
        Eb[(size_t)(orow0 + i * 16 + r) * C_ + (ocol0 + j * 16)] = acc[i][j][r];
}

// ---------------------------------------------------------------------------
// Kernel 2: attnT[b][d][c] = sum_s exp(min_d E_s - E_s[c,d]) / Z_s   (bf16)
// One wave per c-row (4 rows/block), shuffle reductions, sums KSPLIT partials.
// grid (C/4, B).
// ---------------------------------------------------------------------------
__global__ __launch_bounds__(256) void softmax_kernel()
{
  const int b    = blockIdx.y;
  const int c    = blockIdx.x * 4 + (threadIdx.x >> 6);
  const int lane = threadIdx.x & 63;
  const int d0   = lane * 4;

  float a0 = 0.f, a1 = 0.f, a2 = 0.f, a3 = 0.f;
#pragma unroll
  for (int s = 0; s < 3; ++s) {
    float e0 = 0.f, e1 = 0.f, e2 = 0.f, e3 = 0.f;
#pragma unroll
    for (int kc = 0; kc < KSPLIT; ++kc) {
      const float4 ep = *(const float4*)(
          g_Ep + ((((size_t)kc * 3 + s) * B_ + b) * C_ + c) * (size_t)C_ + d0);
      e0 += ep.x; e1 += ep.y; e2 += ep.z; e3 += ep.w;
    }
    float mn = fminf(fminf(e0, e1), fminf(e2, e3));
#pragma unroll
    for (int m = 32; m > 0; m >>= 1) mn = fminf(mn, __shfl_xor(mn, m));
    const float p0 = __expf(mn - e0);   // <= 1; min term gives exactly 1
    const float p1 = __expf(mn - e1);
    const float p2 = __expf(mn - e2);
    const float p3 = __expf(mn - e3);
    float Z = p0 + p1 + p2 + p3;
#pragma unroll
    for (int m = 32; m > 0; m >>= 1) Z += __shfl_xor(Z, m);
    const float rZ = 1.0f / Z;
    a0 += p0 * rZ; a1 += p1 * rZ; a2 += p2 * rZ; a3 += p3 * rZ;
  }
  bf16_t* At = g_attnT + (size_t)b * C_ * C_;   // [d][c], transposed for kernel 3
  At[(size_t)(d0 + 0) * C_ + c] = (bf16_t)a0;
  At[(size_t)(d0 + 1) * C_ + c] = (bf16_t)a1;
  At[(size_t)(d0 + 2) * C_ + c] = (bf16_t)a2;
  At[(size_t)(d0 + 3) * C_ + c] = (bf16_t)a3;
}

// ---------------------------------------------------------------------------
// Kernel 3: M[b][o][d] = sum_c conv_w[o,c] * attnT[b][d][c]   (bf16 out)
// ---------------------------------------------------------------------------
__global__ __launch_bounds__(256) void mconv_kernel()
{
  const int tile = blockIdx.x;  // 0..3
  const int b    = blockIdx.y;
  const int tile_o = (tile & 1) * 128;
  const int tile_d = (tile >> 1) * 128;
  const int tid  = threadIdx.x;
  const int w    = tid >> 6;
  const int lane = tid & 63;
  const int wo   = (w & 1) * 64;
  const int wd   = (w >> 1) * 64;
  const int lrow = lane & 15;
  const int lk   = (lane >> 4) * 8;

  const bf16_t* At = g_attnT + (size_t)b * C_ * C_;
  f32x4 acc[4][4] = {};

  for (int c0 = 0; c0 < C_; c0 += 32) {
    bf16x8 af[4], bfr[4];
#pragma unroll
    for (int i = 0; i < 4; ++i)
      af[i] = *(const bf16x8*)(g_cw + (size_t)(tile_o + wo + i * 16 + lrow) * C_ + c0 + lk);
#pragma unroll
    for (int j = 0; j < 4; ++j)
      bfr[j] = *(const bf16x8*)(At + (size_t)(tile_d + wd + j * 16 + lrow) * C_ + c0 + lk);
#pragma unroll
    for (int i = 0; i < 4; ++i)
#pragma unroll
      for (int j = 0; j < 4; ++j)
        acc[i][j] = MFMA(af[i], bfr[j], acc[i][j]);
  }

  bf16_t* Mb = g_M + (size_t)b * C_ * C_;
  const int orow0 = tile_o + wo + (lane >> 4) * 4;
  const int ocol0 = tile_d + wd + (lane & 15);
#pragma unroll
  for (int i = 0; i < 4; ++i)
#pragma unroll
    for (int j = 0; j < 4; ++j)
#pragma unroll
      for (int r = 0; r < 4; ++r)
        Mb[(size_t)(orow0 + i * 16 + r) * C_ + (ocol0 + j * 16)] = (bf16_t)acc[i][j][r];
}

// ---------------------------------------------------------------------------
// Kernel 4a: P[b][o][n] = sum_d M[b,o,d] * Q[b,d,n]   (bf16 out)
// Clone of energy_kernel's LDS-staged NT structure: A rows = M[o][d],
// B rows = qT[n][d], BK=64, 4 K-steps. grid (N/128, 2, B).
// ---------------------------------------------------------------------------
__global__ __launch_bounds__(256) void pmq_kernel()
{
  const int tile_n = blockIdx.x * 128;          // 0..31
  const int tile_o = blockIdx.y * 128;          // 0..1
  const int b      = blockIdx.z;

  const bf16_t* Mb = g_M  + (size_t)b * C_ * C_;
  const bf16_t* Qt = g_qT + (size_t)b * N_ * C_;

  __shared__ bf16_t As[128][72];  // M rows   [o][d]
  __shared__ bf16_t Bs[128][72];  // qT rows  [n][d]

  const int tid  = threadIdx.x;
  const int w    = tid >> 6;
  const int lane = tid & 63;
  const int wo   = (w & 1) * 64;
  const int wn   = (w >> 1) * 64;
  const int lrow = lane & 15;
  const int lk   = (lane >> 4) * 8;

  const int srow = tid >> 3;        // 0..31
  const int soff = (tid & 7) * 8;   // 0..56

  f32x4 acc[4][4] = {};

  for (int d0 = 0; d0 < C_; d0 += 64) {
    bf16x8 av[4], bv[4];
#pragma unroll
    for (int i = 0; i < 4; ++i) {
      int r = srow + i * 32;
      av[i] = *(const bf16x8*)(Mb + (size_t)(tile_o + r) * C_ + d0 + soff);
      bv[i] = *(const bf16x8*)(Qt + (size_t)(tile_n + r) * C_ + d0 + soff);
    }
    __syncthreads();
#pragma unroll
    for (int i = 0; i < 4; ++i) {
      int r = srow + i * 32;
      *(bf16x8*)(&As[r][soff]) = av[i];
      *(bf16x8*)(&Bs[r][soff]) = bv[i];
    }
    __syncthreads();
#pragma unroll
    for (int kk = 0; kk < 64; kk += 32) {
      bf16x8 af[4], bfr[4];
#pragma unroll
      for (int i = 0; i < 4; ++i)
        af[i] = *(const bf16x8*)(&As[wo + i * 16 + lrow][kk + lk]);
#pragma unroll
      for (int j = 0; j < 4; ++j)
        bfr[j] = *(const bf16x8*)(&Bs[wn + j * 16 + lrow][kk + lk]);
#pragma unroll
      for (int i = 0; i < 4; ++i)
#pragma unroll
        for (int j = 0; j < 4; ++j)
          acc[i][j] = MFMA(af[i], bfr[j], acc[i][j]);
    }
  }

  // C/D layout: col = lane&15 (n), row = (lane>>4)*4 + r (o)
  bf16_t* Pb = g_P + (size_t)b * C_ * N_;
  const int orow0 = tile_o + wo + (lane >> 4) * 4;
  const int ocol0 = tile_n + wn + (lane & 15);
#pragma unroll
  for (int i = 0; i < 4; ++i)
#pragma unroll
    for (int j = 0; j < 4; ++j)
#pragma unroll
      for (int r = 0; r < 4; ++r)
        Pb[(size_t)(orow0 + i * 16 + r) * N_ + (ocol0 + j * 16)] = (bf16_t)acc[i][j][r];
}

// ---------------------------------------------------------------------------
// Kernel 4b: out[b][o][n] = gamma*(P[b,o,n] + bias[o]) + x[b,o,n]
// Pure streaming; one block per (b,o) row; 16 elems/thread, vector I/O.
// grid (B*C).
// ---------------------------------------------------------------------------
__global__ __launch_bounds__(256) void epilogue_kernel(
    const void* __restrict__ xraw, void* __restrict__ outraw)
{
  const int row  = blockIdx.x;            // b*C_ + o
  const int o    = row & (C_ - 1);
  const size_t roff = (size_t)row * N_ + (size_t)threadIdx.x * 16;

  const float g    = g_gamma;
  const float bias = g_cb[o];

  const bf16x8 p0 = *(const bf16x8*)(g_P + roff);
  const bf16x8 p1 = *(const bf16x8*)(g_P + roff + 8);
  float v[16];
#pragma unroll
  for (int k = 0; k < 8; ++k) {
    v[k]     = g * ((float)p0[k] + bias);
    v[8 + k] = g * ((float)p1[k] + bias);
  }

  if (g_mode == MODE_F32) {
    const float* xp = (const float*)xraw + roff;
    float*       op = (float*)outraw + roff;
#pragma unroll
    for (int q4 = 0; q4 < 4; ++q4) {
      float4 xv = *(const float4*)(xp + q4 * 4);
      float4 ov;
      ov.x = v[q4 * 4 + 0] + xv.x;
      ov.y = v[q4 * 4 + 1] + xv.y;
      ov.z = v[q4 * 4 + 2] + xv.z;
      ov.w = v[q4 * 4 + 3] + xv.w;
      *(float4*)(op + q4 * 4) = ov;
    }
  } else {
    const bf16_t* xp = (const bf16_t*)xraw + roff;
    bf16_t*       op = (bf16_t*)outraw + roff;
#pragma unroll
    for (int p = 0; p < 2; ++p) {
      bf16x8 xv = *(const bf16x8*)(xp + p * 8);
      bf16x8 ov;
#pragma unroll
      for (int k = 0; k < 8; ++k)
        ov[k] = (bf16_t)(v[p * 8 + k] + (float)xv[k]);
      *(bf16x8*)(op + p * 8) = ov;
    }
  }
}

// ---------------------------------------------------------------------------
extern "C" void kernel_launch(void* const* d_in, const int* in_sizes, int n_in,
                              void* d_out, int out_size, void* d_ws, size_t ws_size,
                              hipStream_t stream)
{
  const void* x  = d_in[0];
  const void* y  = d_in[1];
  const void* z  = d_in[2];
  const void* cw = d_in[3];
  const void* cb = d_in[4];
  const void* gm = d_in[5];
  (void)d_ws; (void)ws_size;

  detect_kernel   <<<1,                       256, 0, stream>>>((const float*)x);
  convert_big     <<<dim3(8192, 2),           256, 0, stream>>>(y, z);
  convert_params  <<<1,                       256, 0, stream>>>(cw, cb, gm);
  convert_xT      <<<dim3(N_ / 64, C_ / 64, B_), 256, 0, stream>>>(x);
  energy_kernel   <<<dim3(4 * KSPLIT, 3, B_), 256, 0, stream>>>();
  softmax_kernel  <<<dim3(C_ / 4, B_),        256, 0, stream>>>();
  mconv_kernel    <<<dim3(4, B_),             256, 0, stream>>>();
  pmq_kernel      <<<dim3(N_ / 128, 2, B_),   256, 0, stream>>>();
  epilogue_kernel <<<dim3(B_ * C_),           256, 0, stream>>>(x, d_out);
}